// Round 1
// baseline (130.737 us; speedup 1.0000x reference)
//
#include <hip/hip_runtime.h>
#include <math.h>

#define B 8
#define T 512
#define D 1024
#define H 16
#define DH 64

typedef __bf16 bf16;
typedef __attribute__((ext_vector_type(8))) __bf16 bf16x8;
typedef __attribute__((ext_vector_type(4))) float f32x4;

// Async global->LDS, 16 B per lane. LDS dest = wave-uniform base + lane*16.
__device__ __forceinline__ void gld16(const void* g, void* l) {
    __builtin_amdgcn_global_load_lds(
        (const __attribute__((address_space(1))) void*)g,
        (__attribute__((address_space(3))) void*)l, 16, 0, 0);
}

// MFMA 16x16x32 bf16 layouts (HW-verified per guide m89/m120):
//   A[m][k]: m = lane&15, k = (lane>>4)*8 + j
//   B[k][n]: n = lane&15, k = (lane>>4)*8 + j
//   C/D    : col = lane&15, row = (lane>>4)*4 + reg
// gld16 tiles use XOR chunk swizzle (chunk c at c ^ (row & 7));
// pitch-72 tiles (144 B rows) are conflict-free by pitch (<=2-way).
// NOTE: no pointer-array LDS aliases (addrspacecast static-init is rejected);
// buffer parity is folded into arithmetic offsets instead.

#define EXP2SCALE 1.44269504088896f   // log2(e); folded into Q pre-scale

// ---------------------------------------------------------------------------
// Kernel 0: prep (weights) — Wq/Wk/Wv -> per-head [e][d] bf16 (48 blocks);
// Wf -> [n][k] bf16 (256 blocks).  (r6-verified)
// ---------------------------------------------------------------------------
__global__ __launch_bounds__(256) void prep_w(
    const float* __restrict__ Wq, const float* __restrict__ Wk,
    const float* __restrict__ Wv, const float* __restrict__ Wf,
    bf16* __restrict__ WqT, bf16* __restrict__ WkT,
    bf16* __restrict__ WvT, bf16* __restrict__ WfT)
{
    __shared__ bf16 Ts[64 * 72];
    const int blk = blockIdx.x, tid = threadIdx.x;
    if (blk < 48) {
        const int m = blk >> 4, h = blk & 15;
        const float* src = (m == 0 ? Wq : (m == 1 ? Wk : Wv)) + h * 4096;
        bf16* dst = (m == 0 ? WqT : (m == 1 ? WkT : WvT)) + h * 4096;
        for (int i = tid; i < 1024; i += 256) {
            const int d = i >> 4, eq = (i & 15) * 4;
            const float4 w = *(const float4*)(src + d * 64 + eq);
            Ts[(eq + 0) * 72 + d] = (bf16)w.x; Ts[(eq + 1) * 72 + d] = (bf16)w.y;
            Ts[(eq + 2) * 72 + d] = (bf16)w.z; Ts[(eq + 3) * 72 + d] = (bf16)w.w;
        }
        __syncthreads();
        for (int i = tid; i < 512; i += 256) {
            const int e = i >> 3, kc = (i & 7) * 8;
            *(bf16x8*)(dst + e * 64 + kc) = *(const bf16x8*)&Ts[e * 72 + kc];
        }
    } else {
        const int ti = blk - 48, k0 = (ti >> 4) * 64, n0 = (ti & 15) * 64;
        for (int i = tid; i < 1024; i += 256) {
            const int k = i >> 4, nq = (i & 15) * 4;
            const float4 w = *(const float4*)(Wf + (size_t)(k0 + k) * D + n0 + nq);
            Ts[(nq + 0) * 72 + k] = (bf16)w.x; Ts[(nq + 1) * 72 + k] = (bf16)w.y;
            Ts[(nq + 2) * 72 + k] = (bf16)w.z; Ts[(nq + 3) * 72 + k] = (bf16)w.w;
        }
        __syncthreads();
        for (int i = tid; i < 512; i += 256) {
            const int n = i >> 3, kc = (i & 7) * 8;
            *(bf16x8*)(WfT + (size_t)(n0 + n) * D + k0 + kc) = *(const bf16x8*)&Ts[n * 72 + kc];
        }
    }
}

// ---------------------------------------------------------------------------
// Kernel 1: FUSED qkv + flash attention, software-pipelined.
// Grid 512: bh = blk&127 (XCD locality), q-chunk = blk>>7 (128 queries).
// K/V computed in-kernel per 64-key tile from X. Double-buffered Ks/Vts/msk;
// X key-tile for kt+1 prefetched into registers during kt's compute.
// ONE block barrier per tile. No-max softmax via exp2 (Q pre-scaled).
// LDS 78.5 KB -> 2 blocks/CU (= grid residency).
// ---------------------------------------------------------------------------
__global__ __launch_bounds__(256, 2) void qkv_attn(
    const float* __restrict__ X, const int* __restrict__ mask,
    const bf16* __restrict__ WqT, const bf16* __restrict__ WkT,
    const bf16* __restrict__ WvT,
    const float* __restrict__ bq, const float* __restrict__ bk,
    const float* __restrict__ bv,
    bf16* __restrict__ Ob)
{
    __shared__ __align__(16) char smem[80384];
    bf16* Wks = (bf16*)(smem);                 // 8192, persistent
    bf16* Wvs = (bf16*)(smem + 8192);          // 8192, persistent
    // Ks buffers at 16384 + p*9216 ([key][e] p72); Vts at 34816 + p*9216.
    bf16* Pl  = (bf16*)(smem + 53248);         // 4 wave strips 32x72 (18432)
    bf16* Xkt = (bf16*)(smem + 71680);         // 64x64 swizzled (8192)
    int*  msk = (int*)(smem + 79872);          // 2 x 64 ints
    // setup aliases (dead regions; barriers enforce):
    bf16* Wqs   = (bf16*)(smem + 16384);       // = Ks buf 0
    bf16* Xq    = Pl;                          // 16384 <= 18432
    bf16* Stage = Pl;                          // 128 rows p72 (wave strips)
    bf16* Ostage = Pl;

    const int bh = blockIdx.x & 127, q0 = (blockIdx.x >> 7) * 128;
    const int b = bh >> 4, h = bh & 15;
    const int tid = threadIdx.x, wave = tid >> 6, lane = tid & 63;
    const int quad = lane >> 4, l15 = lane & 15;
    const int lr = lane >> 3, lc = lane & 7;
    const int csw = (lc ^ lr) * 8;

    // X key-tile prefetch addressing (wave w -> keys w*16..w*16+15)
    const int pkrow = wave * 16 + (lane >> 2);
    const int pc0 = (lane & 3) * 2;

    float bqr[4], bkr[4], bvr[4];
#pragma unroll
    for (int nt = 0; nt < 4; ++nt) {
        bqr[nt] = bq[h * DH + nt * 16 + l15];
        bkr[nt] = bk[h * DH + nt * 16 + l15];
        bvr[nt] = bv[h * DH + nt * 16 + l15];
    }

    // ---- prefetch tile 0 (X rows + mask) into registers ----
    float4 px0, px1, px2, px3;
    {
        const float* src = X + (size_t)(b * T + pkrow) * D + h * DH + pc0 * 8;
        px0 = *(const float4*)src; px1 = *(const float4*)(src + 4);
        px2 = *(const float4*)(src + 8); px3 = *(const float4*)(src + 12);
    }
    int mreg = (tid < 64) ? mask[(size_t)b * T + tid] : 0;

    // ---- setup: W staging (gld16, swizzled) + X q-tile ----
    {
        const int r1 = wave * 16;
#pragma unroll
        for (int j = 0; j < 2; ++j) {
            gld16(WqT + (size_t)h * 4096 + (r1 + j * 8 + lr) * 64 + csw, &Wqs[(r1 + j * 8) * 64]);
            gld16(WkT + (size_t)h * 4096 + (r1 + j * 8 + lr) * 64 + csw, &Wks[(r1 + j * 8) * 64]);
            gld16(WvT + (size_t)h * 4096 + (r1 + j * 8 + lr) * 64 + csw, &Wvs[(r1 + j * 8) * 64]);
        }
    }
    for (int i = tid; i < 1024; i += 256) {
        const int row = i >> 3, c = i & 7;
        const float* src = X + (size_t)(b * T + q0 + row) * D + h * DH + c * 8;
        const float4 x0 = *(const float4*)src;
        const float4 x1 = *(const float4*)(src + 4);
        bf16x8 t;
        t[0] = (bf16)x0.x; t[1] = (bf16)x0.y; t[2] = (bf16)x0.z; t[3] = (bf16)x0.w;
        t[4] = (bf16)x1.x; t[5] = (bf16)x1.y; t[6] = (bf16)x1.z; t[7] = (bf16)x1.w;
        *(bf16x8*)&Xq[row * 64 + ((c ^ (row & 7)) * 8)] = t;
    }
    __syncthreads();

    // ---- Q = Xq @ WqT (+bias, x 0.125*log2e), C-layout -> Stage -> qf ----
    {
        f32x4 accQ[2][4] = {};
#pragma unroll
        for (int ks = 0; ks < 2; ++ks) {
            bf16x8 af[2], bfr[4];
#pragma unroll
            for (int mt = 0; mt < 2; ++mt) {
                const int row = wave * 32 + mt * 16 + l15;
                af[mt] = *(const bf16x8*)&Xq[row * 64 + (((ks * 4 + quad) ^ (l15 & 7)) * 8)];
            }
#pragma unroll
            for (int nt = 0; nt < 4; ++nt)
                bfr[nt] = *(const bf16x8*)&Wqs[(nt * 16 + l15) * 64 + (((ks * 4 + quad) ^ (l15 & 7)) * 8)];
#pragma unroll
            for (int mt = 0; mt < 2; ++mt)
#pragma unroll
                for (int nt = 0; nt < 4; ++nt)
                    accQ[mt][nt] = __builtin_amdgcn_mfma_f32_16x16x32_bf16(af[mt], bfr[nt], accQ[mt][nt], 0, 0, 0);
        }
        __syncthreads();   // Xq/Wqs reads done everywhere
        const float qs = 0.125f * EXP2SCALE;
#pragma unroll
        for (int mt = 0; mt < 2; ++mt)
#pragma unroll
            for (int nt = 0; nt < 4; ++nt)
#pragma unroll
                for (int reg = 0; reg < 4; ++reg)
                    Stage[(wave * 32 + mt * 16 + quad * 4 + reg) * 72 + nt * 16 + l15] =
                        (bf16)((accQ[mt][nt][reg] + bqr[nt]) * qs);
        __builtin_amdgcn_wave_barrier();
    }
    bf16x8 qf[2][2];
#pragma unroll
    for (int mt = 0; mt < 2; ++mt)
#pragma unroll
        for (int ks = 0; ks < 2; ++ks)
            qf[mt][ks] = *(const bf16x8*)&Stage[(wave * 32 + mt * 16 + l15) * 72 + ks * 32 + quad * 8];

    f32x4 acc[2][4] = {};
    float lst[2][4] = {};

    // ---- K-loop: 8 tiles of 64 keys, pipelined, ONE barrier per tile ----
    for (int kt = 0; kt < 8; ++kt) {
        const int p = kt & 1;
        bf16* Ks  = (bf16*)(smem + 16384 + p * 9216);
        bf16* Vts = (bf16*)(smem + 34816 + p * 9216);

        // stage prefetched X -> Xkt (wave-local), msk -> LDS
        {
            bf16x8 t0, t1;
            t0[0] = (bf16)px0.x; t0[1] = (bf16)px0.y; t0[2] = (bf16)px0.z; t0[3] = (bf16)px0.w;
            t0[4] = (bf16)px1.x; t0[5] = (bf16)px1.y; t0[6] = (bf16)px1.z; t0[7] = (bf16)px1.w;
            t1[0] = (bf16)px2.x; t1[1] = (bf16)px2.y; t1[2] = (bf16)px2.z; t1[3] = (bf16)px2.w;
            t1[4] = (bf16)px3.x; t1[5] = (bf16)px3.y; t1[6] = (bf16)px3.z; t1[7] = (bf16)px3.w;
            *(bf16x8*)&Xkt[pkrow * 64 + ((pc0 ^ (pkrow & 7)) * 8)] = t0;
            *(bf16x8*)&Xkt[pkrow * 64 + (((pc0 + 1) ^ (pkrow & 7)) * 8)] = t1;
            if (tid < 64) msk[p * 64 + tid] = mreg;
        }
        __builtin_amdgcn_wave_barrier();   // wave-local Xkt write->read

        // issue prefetch for tile kt+1 (covers full tile compute)
        if (kt < 7) {
            const float* src = X + (size_t)(b * T + (kt + 1) * 64 + pkrow) * D + h * DH + pc0 * 8;
            px0 = *(const float4*)src; px1 = *(const float4*)(src + 4);
            px2 = *(const float4*)(src + 8); px3 = *(const float4*)(src + 12);
            if (tid < 64) mreg = mask[(size_t)b * T + (kt + 1) * 64 + tid];
        }

        // K/V tiles via MFMA (wave computes its own 16 keys)
        {
            bf16x8 afkv[2];
#pragma unroll
            for (int ks = 0; ks < 2; ++ks)
                afkv[ks] = *(const bf16x8*)&Xkt[(wave * 16 + l15) * 64 + (((ks * 4 + quad) ^ (l15 & 7)) * 8)];
            f32x4 accK[4] = {}, accV[4] = {};
#pragma unroll
            for (int ks = 0; ks < 2; ++ks)
#pragma unroll
                for (int nt = 0; nt < 4; ++nt) {
                    const bf16x8 bk8 = *(const bf16x8*)&Wks[(nt * 16 + l15) * 64 + (((ks * 4 + quad) ^ (l15 & 7)) * 8)];
                    accK[nt] = __builtin_amdgcn_mfma_f32_16x16x32_bf16(afkv[ks], bk8, accK[nt], 0, 0, 0);
                    const bf16x8 bv8 = *(const bf16x8*)&Wvs[(nt * 16 + l15) * 64 + (((ks * 4 + quad) ^ (l15 & 7)) * 8)];
                    accV[nt] = __builtin_amdgcn_mfma_f32_16x16x32_bf16(afkv[ks], bv8, accV[nt], 0, 0, 0);
                }
#pragma unroll
            for (int nt = 0; nt < 4; ++nt)
#pragma unroll
                for (int reg = 0; reg < 4; ++reg) {
                    const int key = wave * 16 + quad * 4 + reg;
                    const int e = nt * 16 + l15;
                    Ks[key * 72 + e] = (bf16)(accK[nt][reg] + bkr[nt]);
                    Vts[e * 72 + key] = (bf16)(accV[nt][reg] + bvr[nt]);
                }
        }
        __syncthreads();   // the only block barrier: K/V (+msk) visible

        // S = Q K^T; p = mask ? exp2(s) : 0; P -> own wave strip
        bf16* Plw = Pl + wave * (32 * 72);
        {
            bf16x8 kf[4][2];
#pragma unroll
            for (int nt = 0; nt < 4; ++nt)
#pragma unroll
                for (int ks = 0; ks < 2; ++ks)
                    kf[nt][ks] = *(const bf16x8*)&Ks[(nt * 16 + l15) * 72 + ks * 32 + quad * 8];
            int mv[4];
#pragma unroll
            for (int nt = 0; nt < 4; ++nt) mv[nt] = msk[p * 64 + nt * 16 + l15];
#pragma unroll
            for (int mt = 0; mt < 2; ++mt) {
                f32x4 s[4] = {};
#pragma unroll
                for (int ks = 0; ks < 2; ++ks)
#pragma unroll
                    for (int nt = 0; nt < 4; ++nt)
                        s[nt] = __builtin_amdgcn_mfma_f32_16x16x32_bf16(qf[mt][ks], kf[nt][ks], s[nt], 0, 0, 0);
#pragma unroll
                for (int nt = 0; nt < 4; ++nt)
#pragma unroll
                    for (int reg = 0; reg < 4; ++reg) {
                        const float pv = (mv[nt] > 0) ? exp2f(s[nt][reg]) : 0.f;
                        lst[mt][reg] += pv;
                        Plw[(mt * 16 + quad * 4 + reg) * 72 + nt * 16 + l15] = (bf16)pv;
                    }
            }
        }
        __builtin_amdgcn_wave_barrier();   // wave-local P write->read

        // O += P V
#pragma unroll
        for (int kc = 0; kc < 2; ++kc) {
            const bf16x8 pf0 = *(const bf16x8*)&Plw[(l15) * 72 + kc * 32 + quad * 8];
            const bf16x8 pf1 = *(const bf16x8*)&Plw[(16 + l15) * 72 + kc * 32 + quad * 8];
#pragma unroll
            for (int nt = 0; nt < 4; ++nt) {
                const bf16x8 vf = *(const bf16x8*)&Vts[(nt * 16 + l15) * 72 + kc * 32 + quad * 8];
                acc[0][nt] = __builtin_amdgcn_mfma_f32_16x16x32_bf16(pf0, vf, acc[0][nt], 0, 0, 0);
                acc[1][nt] = __builtin_amdgcn_mfma_f32_16x16x32_bf16(pf1, vf, acc[1][nt], 0, 0, 0);
            }
        }
    }

    // ---- epilogue: normalize -> Ostage (own strip) -> coalesced b128 ----
    __builtin_amdgcn_wave_barrier();
#pragma unroll
    for (int mt = 0; mt < 2; ++mt)
#pragma unroll
        for (int reg = 0; reg < 4; ++reg) {
            float l = lst[mt][reg];
            l += __shfl_xor(l, 1);
            l += __shfl_xor(l, 2);
            l += __shfl_xor(l, 4);
            l += __shfl_xor(l, 8);
            const float inv = 1.f / l;
            const int row = wave * 32 + mt * 16 + quad * 4 + reg;   // own strip
#pragma unroll
            for (int nt = 0; nt < 4; ++nt)
                Ostage[row * 72 + nt * 16 + l15] = (bf16)(acc[mt][nt][reg] * inv);
        }
    __syncthreads();
    for (int i = tid; i < 1024; i += 256) {
        const int row = i >> 3, c = (i & 7) * 8;
        *(bf16x8*)(Ob + ((size_t)b * T + q0 + row) * D + h * DH + c) =
            *(const bf16x8*)&Ostage[row * 72 + c];
    }
}

// ---------------------------------------------------------------------------
// Kernel 2: fusion GEMM, double-buffered BK=64. out = Ob @ WfT^T + bf.
// 128M x 64N tile, gld16 swizzled staging, one barrier per K-iter.
// ---------------------------------------------------------------------------
__global__ __launch_bounds__(256, 2) void fuse_mfma(
    const bf16* __restrict__ Ob, const bf16* __restrict__ WfT,
    const float* __restrict__ bfv, float* __restrict__ out)
{
    __shared__ __align__(16) char smem[49152];
    // As buffers at buf*16384 (128x64 p64); Bs at 32768 + buf*8192 (64x64 p64).

    const int col0 = blockIdx.x * 64;
    const int row0 = blockIdx.y * 128;
    const int tid = threadIdx.x, wave = tid >> 6, lane = tid & 63;
    const int quad = lane >> 4, l15 = lane & 15;
    const int lr = lane >> 3, lc = lane & 7;
    const int wm = wave * 32;

    f32x4 acc[2][4] = {};

    auto stage = [&](int k0, int buf) {
        bf16* As = (bf16*)(smem + buf * 16384);
        bf16* Bs = (bf16*)(smem + 32768 + buf * 8192);
#pragma unroll
        for (int j = 0; j < 4; ++j) {
            const int row = wm + j * 8 + lr;
            gld16(Ob + (size_t)(row0 + row) * D + k0 + ((lc ^ (row & 7)) * 8),
                  &As[(wm + j * 8) * 64]);
        }
#pragma unroll
        for (int j = 0; j < 2; ++j) {
            const int row = wave * 16 + j * 8 + lr;
            gld16(WfT + (size_t)(col0 + row) * D + k0 + ((lc ^ (row & 7)) * 8),
                  &Bs[(wave * 16 + j * 8) * 64]);
        }
    };

    stage(0, 0);
    __syncthreads();

    for (int i = 0; i < 16; ++i) {
        const int buf = i & 1;
        if (i < 15) stage((i + 1) * 64, buf ^ 1);   // overlap with compute
        bf16* As = (bf16*)(smem + buf * 16384);
        bf16* Bs = (bf16*)(smem + 32768 + buf * 8192);
#pragma unroll
        for (int ks = 0; ks < 2; ++ks) {
            bf16x8 af[2], bfr[4];
#pragma unroll
            for (int mt = 0; mt < 2; ++mt) {
                const int row = wm + mt * 16 + l15;
                af[mt] = *(const bf16x8*)&As[row * 64 + (((ks * 4 + quad) ^ (l15 & 7)) * 8)];
            }
#pragma unroll
            for (int nt = 0; nt < 4; ++nt)
                bfr[nt] = *(const bf16x8*)&Bs[(nt * 16 + l15) * 64 + (((ks * 4 + quad) ^ (l15 & 7)) * 8)];
#pragma unroll
            for (int mt = 0; mt < 2; ++mt)
#pragma unroll
                for (int nt = 0; nt < 4; ++nt)
                    acc[mt][nt] = __builtin_amdgcn_mfma_f32_16x16x32_bf16(af[mt], bfr[nt], acc[mt][nt], 0, 0, 0);
        }
        __syncthreads();   // next-buf loads landed; cur-buf reads done
    }

    // Epilogue: +bias -> LDS fp32 p68 -> float4 stores.
    float* Ofs = (float*)smem;
    float bias[4];
#pragma unroll
    for (int nt = 0; nt < 4; ++nt) bias[nt] = bfv[col0 + nt * 16 + l15];
#pragma unroll
    for (int mt = 0; mt < 2; ++mt)
#pragma unroll
        for (int reg = 0; reg < 4; ++reg) {
            const int row = wm + mt * 16 + quad * 4 + reg;
#pragma unroll
            for (int nt = 0; nt < 4; ++nt)
                Ofs[row * 68 + nt * 16 + l15] = acc[mt][nt][reg] + bias[nt];
        }
    __syncthreads();
    for (int i = tid; i < 2048; i += 256) {
        const int row = i >> 4, c = (i & 15) * 4;
        *(float4*)(out + (size_t)(row0 + row) * D + col0 + c) = *(const float4*)&Ofs[row * 68 + c];
    }
}

// ---------------------------------------------------------------------------
extern "C" void kernel_launch(void* const* d_in, const int* in_sizes, int n_in,
                              void* d_out, int out_size, void* d_ws, size_t ws_size,
                              hipStream_t stream) {
    const float* X   = (const float*)d_in[0];
    const int* mask  = (const int*)d_in[1];
    const float* Wq  = (const float*)d_in[2];
    const float* bq  = (const float*)d_in[3];
    const float* Wk  = (const float*)d_in[4];
    const float* bk  = (const float*)d_in[5];
    const float* Wv  = (const float*)d_in[6];
    const float* bv  = (const float*)d_in[7];
    const float* Wf  = (const float*)d_in[8];
    const float* bfv = (const float*)d_in[9];
    float* out = (float*)d_out;

    bf16* wsb = (bf16*)d_ws;
    const size_t QN = (size_t)B * H * T * DH;   // 4,194,304
    bf16* Ob  = wsb;
    bf16* WfT = wsb + QN;                       // 1,048,576
    bf16* WqT = WfT + (size_t)D * D;
    bf16* WkT = WqT + H * DH * DH;              // 65,536 each
    bf16* WvT = WkT + H * DH * DH;

    prep_w<<<dim3(304), 256, 0, stream>>>(Wq, Wk, Wv, Wf, WqT, WkT, WvT, WfT);
    qkv_attn<<<dim3(512), 256, 0, stream>>>(X, mask, WqT, WkT, WvT, bq, bk, bv, Ob);
    fuse_mfma<<<dim3(D / 64, (B * T) / 128), 256, 0, stream>>>(Ob, WfT, bfv, out);
}

// Round 2
// 128.369 us; speedup vs baseline: 1.0184x; 1.0184x over previous
//
#include <hip/hip_runtime.h>
#include <math.h>

#define B 8
#define T 512
#define D 1024
#define H 16
#define DH 64

typedef __bf16 bf16;
typedef __attribute__((ext_vector_type(8))) __bf16 bf16x8;
typedef __attribute__((ext_vector_type(4))) __bf16 bf16x4;
typedef __attribute__((ext_vector_type(4))) float f32x4;

// Async global->LDS, 16 B per lane. LDS dest = wave-uniform base + lane*16.
__device__ __forceinline__ void gld16(const void* g, void* l) {
    __builtin_amdgcn_global_load_lds(
        (const __attribute__((address_space(1))) void*)g,
        (__attribute__((address_space(3))) void*)l, 16, 0, 0);
}

// MFMA 16x16x32 bf16 layouts (HW-verified per guide m89/m120):
//   A[m][k]: m = lane&15, k = (lane>>4)*8 + j
//   B[k][n]: n = lane&15, k = (lane>>4)*8 + j   (same lane map as A!)
//   C/D    : col = lane&15, row = (lane>>4)*4 + reg
// => swapping mfma operand order transposes D without touching fragments.
// gld16 tiles use XOR chunk swizzle (chunk c at c ^ (row & 7));
// pitch-72 tiles (144 B rows) are conflict-free by pitch (<=2-way).

#define EXP2SCALE 1.44269504088896f   // log2(e); folded into Q pre-scale

// ---------------------------------------------------------------------------
// Kernel 0: prep (weights) — unchanged (r6-verified).
// ---------------------------------------------------------------------------
__global__ __launch_bounds__(256) void prep_w(
    const float* __restrict__ Wq, const float* __restrict__ Wk,
    const float* __restrict__ Wv, const float* __restrict__ Wf,
    bf16* __restrict__ WqT, bf16* __restrict__ WkT,
    bf16* __restrict__ WvT, bf16* __restrict__ WfT)
{
    __shared__ bf16 Ts[64 * 72];
    const int blk = blockIdx.x, tid = threadIdx.x;
    if (blk < 48) {
        const int m = blk >> 4, h = blk & 15;
        const float* src = (m == 0 ? Wq : (m == 1 ? Wk : Wv)) + h * 4096;
        bf16* dst = (m == 0 ? WqT : (m == 1 ? WkT : WvT)) + h * 4096;
        for (int i = tid; i < 1024; i += 256) {
            const int d = i >> 4, eq = (i & 15) * 4;
            const float4 w = *(const float4*)(src + d * 64 + eq);
            Ts[(eq + 0) * 72 + d] = (bf16)w.x; Ts[(eq + 1) * 72 + d] = (bf16)w.y;
            Ts[(eq + 2) * 72 + d] = (bf16)w.z; Ts[(eq + 3) * 72 + d] = (bf16)w.w;
        }
        __syncthreads();
        for (int i = tid; i < 512; i += 256) {
            const int e = i >> 3, kc = (i & 7) * 8;
            *(bf16x8*)(dst + e * 64 + kc) = *(const bf16x8*)&Ts[e * 72 + kc];
        }
    } else {
        const int ti = blk - 48, k0 = (ti >> 4) * 64, n0 = (ti & 15) * 64;
        for (int i = tid; i < 1024; i += 256) {
            const int k = i >> 4, nq = (i & 15) * 4;
            const float4 w = *(const float4*)(Wf + (size_t)(k0 + k) * D + n0 + nq);
            Ts[(nq + 0) * 72 + k] = (bf16)w.x; Ts[(nq + 1) * 72 + k] = (bf16)w.y;
            Ts[(nq + 2) * 72 + k] = (bf16)w.z; Ts[(nq + 3) * 72 + k] = (bf16)w.w;
        }
        __syncthreads();
        for (int i = tid; i < 512; i += 256) {
            const int n = i >> 3, kc = (i & 7) * 8;
            *(bf16x8*)(WfT + (size_t)(n0 + n) * D + k0 + kc) = *(const bf16x8*)&Ts[n * 72 + kc];
        }
    }
}

// ---------------------------------------------------------------------------
// Kernel 1: FUSED qkv + flash attention.
// R1 changes: packed b64 LDS writes everywhere (K via swapped mfma operands,
// V already reg-consecutive, P via swapped S-mfma); bk dropped (cancels in
// softmax exactly); bv moved to epilogue (exact). 64 -> 16 LDS write ops per
// lane per tile.
// ---------------------------------------------------------------------------
__global__ __launch_bounds__(256, 2) void qkv_attn(
    const float* __restrict__ X, const int* __restrict__ mask,
    const bf16* __restrict__ WqT, const bf16* __restrict__ WkT,
    const bf16* __restrict__ WvT,
    const float* __restrict__ bq, const float* __restrict__ bk,
    const float* __restrict__ bv,
    bf16* __restrict__ Ob)
{
    __shared__ __align__(16) char smem[80384];
    bf16* Wks = (bf16*)(smem);                 // 8192, persistent
    bf16* Wvs = (bf16*)(smem + 8192);          // 8192, persistent
    // Ks buffers at 16384 + p*9216 ([key][e] p72); Vts at 34816 + p*9216.
    bf16* Pl  = (bf16*)(smem + 53248);         // 4 wave strips 32x72 (18432)
    bf16* Xkt = (bf16*)(smem + 71680);         // 64x64 swizzled (8192)
    int*  msk = (int*)(smem + 79872);          // 2 x 64 ints
    // setup aliases (dead regions; barriers enforce):
    bf16* Wqs   = (bf16*)(smem + 16384);       // = Ks buf 0
    bf16* Xq    = Pl;                          // 16384 <= 18432
    bf16* Stage = Pl;                          // 128 rows p72 (wave strips)
    bf16* Ostage = Pl;

    const int bh = blockIdx.x & 127, q0 = (blockIdx.x >> 7) * 128;
    const int b = bh >> 4, h = bh & 15;
    const int tid = threadIdx.x, wave = tid >> 6, lane = tid & 63;
    const int quad = lane >> 4, l15 = lane & 15;
    const int lr = lane >> 3, lc = lane & 7;
    const int csw = (lc ^ lr) * 8;
    (void)bk;   // K bias adds Q·bk uniformly across keys -> cancels in softmax

    // X key-tile prefetch addressing (wave w -> keys w*16..w*16+15)
    const int pkrow = wave * 16 + (lane >> 2);
    const int pc0 = (lane & 3) * 2;

    float bqr[4], bvr[4];
#pragma unroll
    for (int nt = 0; nt < 4; ++nt) {
        bqr[nt] = bq[h * DH + nt * 16 + l15];
        bvr[nt] = bv[h * DH + nt * 16 + l15];
    }

    // ---- prefetch tile 0 (X rows + mask) into registers ----
    float4 px0, px1, px2, px3;
    {
        const float* src = X + (size_t)(b * T + pkrow) * D + h * DH + pc0 * 8;
        px0 = *(const float4*)src; px1 = *(const float4*)(src + 4);
        px2 = *(const float4*)(src + 8); px3 = *(const float4*)(src + 12);
    }
    int mreg = (tid < 64) ? mask[(size_t)b * T + tid] : 0;

    // ---- setup: W staging (gld16, swizzled) + X q-tile ----
    {
        const int r1 = wave * 16;
#pragma unroll
        for (int j = 0; j < 2; ++j) {
            gld16(WqT + (size_t)h * 4096 + (r1 + j * 8 + lr) * 64 + csw, &Wqs[(r1 + j * 8) * 64]);
            gld16(WkT + (size_t)h * 4096 + (r1 + j * 8 + lr) * 64 + csw, &Wks[(r1 + j * 8) * 64]);
            gld16(WvT + (size_t)h * 4096 + (r1 + j * 8 + lr) * 64 + csw, &Wvs[(r1 + j * 8) * 64]);
        }
    }
    for (int i = tid; i < 1024; i += 256) {
        const int row = i >> 3, c = i & 7;
        const float* src = X + (size_t)(b * T + q0 + row) * D + h * DH + c * 8;
        const float4 x0 = *(const float4*)src;
        const float4 x1 = *(const float4*)(src + 4);
        bf16x8 t;
        t[0] = (bf16)x0.x; t[1] = (bf16)x0.y; t[2] = (bf16)x0.z; t[3] = (bf16)x0.w;
        t[4] = (bf16)x1.x; t[5] = (bf16)x1.y; t[6] = (bf16)x1.z; t[7] = (bf16)x1.w;
        *(bf16x8*)&Xq[row * 64 + ((c ^ (row & 7)) * 8)] = t;
    }
    __syncthreads();

    // ---- Q = Xq @ WqT (+bias, x 0.125*log2e), C-layout -> Stage -> qf ----
    {
        f32x4 accQ[2][4] = {};
#pragma unroll
        for (int ks = 0; ks < 2; ++ks) {
            bf16x8 af[2], bfr[4];
#pragma unroll
            for (int mt = 0; mt < 2; ++mt) {
                const int row = wave * 32 + mt * 16 + l15;
                af[mt] = *(const bf16x8*)&Xq[row * 64 + (((ks * 4 + quad) ^ (l15 & 7)) * 8)];
            }
#pragma unroll
            for (int nt = 0; nt < 4; ++nt)
                bfr[nt] = *(const bf16x8*)&Wqs[(nt * 16 + l15) * 64 + (((ks * 4 + quad) ^ (l15 & 7)) * 8)];
#pragma unroll
            for (int mt = 0; mt < 2; ++mt)
#pragma unroll
                for (int nt = 0; nt < 4; ++nt)
                    accQ[mt][nt] = __builtin_amdgcn_mfma_f32_16x16x32_bf16(af[mt], bfr[nt], accQ[mt][nt], 0, 0, 0);
        }
        __syncthreads();   // Xq/Wqs reads done everywhere
        const float qs = 0.125f * EXP2SCALE;
#pragma unroll
        for (int mt = 0; mt < 2; ++mt)
#pragma unroll
            for (int nt = 0; nt < 4; ++nt)
#pragma unroll
                for (int reg = 0; reg < 4; ++reg)
                    Stage[(wave * 32 + mt * 16 + quad * 4 + reg) * 72 + nt * 16 + l15] =
                        (bf16)((accQ[mt][nt][reg] + bqr[nt]) * qs);
        __builtin_amdgcn_wave_barrier();
    }
    bf16x8 qf[2][2];
#pragma unroll
    for (int mt = 0; mt < 2; ++mt)
#pragma unroll
        for (int ks = 0; ks < 2; ++ks)
            qf[mt][ks] = *(const bf16x8*)&Stage[(wave * 32 + mt * 16 + l15) * 72 + ks * 32 + quad * 8];

    f32x4 acc[2][4] = {};
    float lst2[2] = {0.f, 0.f};   // row-sum partial for q = mt*16+l15 (this lane's quads' keys)

    // ---- K-loop: 8 tiles of 64 keys, pipelined, ONE barrier per tile ----
    for (int kt = 0; kt < 8; ++kt) {
        const int p = kt & 1;
        bf16* Ks  = (bf16*)(smem + 16384 + p * 9216);
        bf16* Vts = (bf16*)(smem + 34816 + p * 9216);

        // stage prefetched X -> Xkt (wave-local), msk -> LDS
        {
            bf16x8 t0, t1;
            t0[0] = (bf16)px0.x; t0[1] = (bf16)px0.y; t0[2] = (bf16)px0.z; t0[3] = (bf16)px0.w;
            t0[4] = (bf16)px1.x; t0[5] = (bf16)px1.y; t0[6] = (bf16)px1.z; t0[7] = (bf16)px1.w;
            t1[0] = (bf16)px2.x; t1[1] = (bf16)px2.y; t1[2] = (bf16)px2.z; t1[3] = (bf16)px2.w;
            t1[4] = (bf16)px3.x; t1[5] = (bf16)px3.y; t1[6] = (bf16)px3.z; t1[7] = (bf16)px3.w;
            *(bf16x8*)&Xkt[pkrow * 64 + ((pc0 ^ (pkrow & 7)) * 8)] = t0;
            *(bf16x8*)&Xkt[pkrow * 64 + (((pc0 + 1) ^ (pkrow & 7)) * 8)] = t1;
            if (tid < 64) msk[p * 64 + tid] = mreg;
        }
        __builtin_amdgcn_wave_barrier();   // wave-local Xkt write->read

        // issue prefetch for tile kt+1 (covers full tile compute)
        if (kt < 7) {
            const float* src = X + (size_t)(b * T + (kt + 1) * 64 + pkrow) * D + h * DH + pc0 * 8;
            px0 = *(const float4*)src; px1 = *(const float4*)(src + 4);
            px2 = *(const float4*)(src + 8); px3 = *(const float4*)(src + 12);
            if (tid < 64) mreg = mask[(size_t)b * T + (kt + 1) * 64 + tid];
        }

        // K/V tiles via MFMA (wave computes its own 16 keys).
        // K: swapped operands -> D[e][key], reg runs along e -> b64 pack.
        // V: normal operands  -> D[key][e], reg runs along key -> b64 pack
        //    into the transposed [e][key] store.
        {
            bf16x8 afkv[2];
#pragma unroll
            for (int ks = 0; ks < 2; ++ks)
                afkv[ks] = *(const bf16x8*)&Xkt[(wave * 16 + l15) * 64 + (((ks * 4 + quad) ^ (l15 & 7)) * 8)];
            f32x4 accK[4] = {}, accV[4] = {};
#pragma unroll
            for (int ks = 0; ks < 2; ++ks)
#pragma unroll
                for (int nt = 0; nt < 4; ++nt) {
                    const bf16x8 bk8 = *(const bf16x8*)&Wks[(nt * 16 + l15) * 64 + (((ks * 4 + quad) ^ (l15 & 7)) * 8)];
                    accK[nt] = __builtin_amdgcn_mfma_f32_16x16x32_bf16(bk8, afkv[ks], accK[nt], 0, 0, 0);
                    const bf16x8 bv8 = *(const bf16x8*)&Wvs[(nt * 16 + l15) * 64 + (((ks * 4 + quad) ^ (l15 & 7)) * 8)];
                    accV[nt] = __builtin_amdgcn_mfma_f32_16x16x32_bf16(afkv[ks], bv8, accV[nt], 0, 0, 0);
                }
#pragma unroll
            for (int nt = 0; nt < 4; ++nt) {
                // accK[nt][reg] = K[e = nt*16+quad*4+reg][key = wave*16+l15]
                bf16x4 kp;
#pragma unroll
                for (int reg = 0; reg < 4; ++reg) kp[reg] = (bf16)accK[nt][reg];
                *(bf16x4*)&Ks[(wave * 16 + l15) * 72 + nt * 16 + quad * 4] = kp;
                // accV[nt][reg] = V[key = wave*16+quad*4+reg][e = nt*16+l15]
                bf16x4 vp;
#pragma unroll
                for (int reg = 0; reg < 4; ++reg) vp[reg] = (bf16)accV[nt][reg];
                *(bf16x4*)&Vts[(nt * 16 + l15) * 72 + wave * 16 + quad * 4] = vp;
            }
        }
        __syncthreads();   // the only block barrier: K/V (+msk) visible

        // S^T = K Q^T (swapped): lane holds S[key=nt*16+quad*4+reg][q=mt*16+l15]
        // -> P write is reg-consecutive along key in [q][key] storage.
        bf16* Plw = Pl + wave * (32 * 72);
        {
            bf16x8 kf[4][2];
#pragma unroll
            for (int nt = 0; nt < 4; ++nt)
#pragma unroll
                for (int ks = 0; ks < 2; ++ks)
                    kf[nt][ks] = *(const bf16x8*)&Ks[(nt * 16 + l15) * 72 + ks * 32 + quad * 8];
            int4 mv4[4];
#pragma unroll
            for (int nt = 0; nt < 4; ++nt)
                mv4[nt] = *(const int4*)&msk[p * 64 + nt * 16 + quad * 4];
#pragma unroll
            for (int mt = 0; mt < 2; ++mt) {
                f32x4 s[4] = {};
#pragma unroll
                for (int ks = 0; ks < 2; ++ks)
#pragma unroll
                    for (int nt = 0; nt < 4; ++nt)
                        s[nt] = __builtin_amdgcn_mfma_f32_16x16x32_bf16(kf[nt][ks], qf[mt][ks], s[nt], 0, 0, 0);
#pragma unroll
                for (int nt = 0; nt < 4; ++nt) {
                    bf16x4 pp;
                    const float p0 = (mv4[nt].x > 0) ? exp2f(s[nt][0]) : 0.f;
                    const float p1 = (mv4[nt].y > 0) ? exp2f(s[nt][1]) : 0.f;
                    const float p2 = (mv4[nt].z > 0) ? exp2f(s[nt][2]) : 0.f;
                    const float p3 = (mv4[nt].w > 0) ? exp2f(s[nt][3]) : 0.f;
                    lst2[mt] += (p0 + p1) + (p2 + p3);
                    pp[0] = (bf16)p0; pp[1] = (bf16)p1; pp[2] = (bf16)p2; pp[3] = (bf16)p3;
                    *(bf16x4*)&Plw[(mt * 16 + l15) * 72 + nt * 16 + quad * 4] = pp;
                }
            }
        }
        __builtin_amdgcn_wave_barrier();   // wave-local P write->read

        // O += P V   (A-frag reads of P unchanged: row = q, contiguous keys)
#pragma unroll
        for (int kc = 0; kc < 2; ++kc) {
            const bf16x8 pf0 = *(const bf16x8*)&Plw[(l15) * 72 + kc * 32 + quad * 8];
            const bf16x8 pf1 = *(const bf16x8*)&Plw[(16 + l15) * 72 + kc * 32 + quad * 8];
#pragma unroll
            for (int nt = 0; nt < 4; ++nt) {
                const bf16x8 vf = *(const bf16x8*)&Vts[(nt * 16 + l15) * 72 + kc * 32 + quad * 8];
                acc[0][nt] = __builtin_amdgcn_mfma_f32_16x16x32_bf16(pf0, vf, acc[0][nt], 0, 0, 0);
                acc[1][nt] = __builtin_amdgcn_mfma_f32_16x16x32_bf16(pf1, vf, acc[1][nt], 0, 0, 0);
            }
        }
    }

    // ---- epilogue: reduce l across quads, redistribute, +bv, store ----
    __builtin_amdgcn_wave_barrier();
    float inv_r[2][4];
#pragma unroll
    for (int mt = 0; mt < 2; ++mt) {
        float l = lst2[mt];
        l += __shfl_xor(l, 16);
        l += __shfl_xor(l, 32);           // all quads now hold sum for q = mt*16+l15
        const float inv = 1.f / l;
#pragma unroll
        for (int reg = 0; reg < 4; ++reg)
            inv_r[mt][reg] = __shfl(inv, (lane & 48) | (quad * 4 + reg));
    }
#pragma unroll
    for (int mt = 0; mt < 2; ++mt)
#pragma unroll
        for (int reg = 0; reg < 4; ++reg) {
            const int row = wave * 32 + mt * 16 + quad * 4 + reg;   // own strip
#pragma unroll
            for (int nt = 0; nt < 4; ++nt)
                Ostage[row * 72 + nt * 16 + l15] =
                    (bf16)(acc[mt][nt][reg] * inv_r[mt][reg] + bvr[nt]);
        }
    __syncthreads();
    for (int i = tid; i < 1024; i += 256) {
        const int row = i >> 3, c = (i & 7) * 8;
        *(bf16x8*)(Ob + ((size_t)b * T + q0 + row) * D + h * DH + c) =
            *(const bf16x8*)&Ostage[row * 72 + c];
    }
}

// ---------------------------------------------------------------------------
// Kernel 2: fusion GEMM, double-buffered BK=64, 128M x 128N tile (R1: was
// 64N -> staging bytes per MFMA halved; 8 gld16 : 32 MFMA per wave-iter).
// ---------------------------------------------------------------------------
__global__ __launch_bounds__(256, 2) void fuse_mfma(
    const bf16* __restrict__ Ob, const bf16* __restrict__ WfT,
    const float* __restrict__ bfv, float* __restrict__ out)
{
    __shared__ __align__(16) char smem[65536];
    // As buffers at buf*16384 (128x64 p64); Bs at 32768 + buf*16384 (128x64 p64).

    const int col0 = blockIdx.x * 128;
    const int row0 = blockIdx.y * 128;
    const int tid = threadIdx.x, wave = tid >> 6, lane = tid & 63;
    const int quad = lane >> 4, l15 = lane & 15;
    const int lr = lane >> 3, lc = lane & 7;
    const int wm = wave * 32;

    f32x4 acc[2][8] = {};

    auto stage = [&](int k0, int buf) {
        bf16* As = (bf16*)(smem + buf * 16384);
        bf16* Bs = (bf16*)(smem + 32768 + buf * 16384);
#pragma unroll
        for (int j = 0; j < 4; ++j) {
            const int row = wm + j * 8 + lr;
            gld16(Ob + (size_t)(row0 + row) * D + k0 + ((lc ^ (row & 7)) * 8),
                  &As[(wm + j * 8) * 64]);
            gld16(WfT + (size_t)(col0 + row) * D + k0 + ((lc ^ (row & 7)) * 8),
                  &Bs[(wm + j * 8) * 64]);
        }
    };

    stage(0, 0);
    __syncthreads();

    for (int i = 0; i < 16; ++i) {
        const int buf = i & 1;
        if (i < 15) stage((i + 1) * 64, buf ^ 1);   // overlap with compute
        bf16* As = (bf16*)(smem + buf * 16384);
        bf16* Bs = (bf16*)(smem + 32768 + buf * 16384);
#pragma unroll
        for (int ks = 0; ks < 2; ++ks) {
            bf16x8 af[2], bfr[8];
#pragma unroll
            for (int mt = 0; mt < 2; ++mt) {
                const int row = wm + mt * 16 + l15;
                af[mt] = *(const bf16x8*)&As[row * 64 + (((ks * 4 + quad) ^ (l15 & 7)) * 8)];
            }
#pragma unroll
            for (int nt = 0; nt < 8; ++nt)
                bfr[nt] = *(const bf16x8*)&Bs[(nt * 16 + l15) * 64 + (((ks * 4 + quad) ^ (l15 & 7)) * 8)];
#pragma unroll
            for (int mt = 0; mt < 2; ++mt)
#pragma unroll
                for (int nt = 0; nt < 8; ++nt)
                    acc[mt][nt] = __builtin_amdgcn_mfma_f32_16x16x32_bf16(af[mt], bfr[nt], acc[mt][nt], 0, 0, 0);
        }
        __syncthreads();   // next-buf loads landed; cur-buf reads done
    }

    // Epilogue: +bias -> LDS fp32 p68 -> float4 stores; two 64-col passes.
    float* Ofs = (float*)smem;
    float bias[8];
#pragma unroll
    for (int nt = 0; nt < 8; ++nt) bias[nt] = bfv[col0 + nt * 16 + l15];
#pragma unroll
    for (int cp = 0; cp < 2; ++cp) {
        if (cp) __syncthreads();   // pass-0 stores done before overwrite
#pragma unroll
        for (int mt = 0; mt < 2; ++mt)
#pragma unroll
            for (int reg = 0; reg < 4; ++reg) {
                const int row = wm + mt * 16 + quad * 4 + reg;
#pragma unroll
                for (int nn = 0; nn < 4; ++nn)
                    Ofs[row * 68 + nn * 16 + l15] = acc[mt][cp * 4 + nn][reg] + bias[cp * 4 + nn];
            }
        __syncthreads();
        for (int i = tid; i < 2048; i += 256) {
            const int row = i >> 4, c = (i & 15) * 4;
            *(float4*)(out + (size_t)(row0 + row) * D + col0 + cp * 64 + c) =
                *(const float4*)&Ofs[row * 68 + c];
        }
    }
}

// ---------------------------------------------------------------------------
extern "C" void kernel_launch(void* const* d_in, const int* in_sizes, int n_in,
                              void* d_out, int out_size, void* d_ws, size_t ws_size,
                              hipStream_t stream) {
    const float* X   = (const float*)d_in[0];
    const int* mask  = (const int*)d_in[1];
    const float* Wq  = (const float*)d_in[2];
    const float* bq  = (const float*)d_in[3];
    const float* Wk  = (const float*)d_in[4];
    const float* bk  = (const float*)d_in[5];
    const float* Wv  = (const float*)d_in[6];
    const float* bv  = (const float*)d_in[7];
    const float* Wf  = (const float*)d_in[8];
    const float* bfv = (const float*)d_in[9];
    float* out = (float*)d_out;

    bf16* wsb = (bf16*)d_ws;
    const size_t QN = (size_t)B * H * T * DH;   // 4,194,304
    bf16* Ob  = wsb;
    bf16* WfT = wsb + QN;                       // 1,048,576
    bf16* WqT = WfT + (size_t)D * D;
    bf16* WkT = WqT + H * DH * DH;              // 65,536 each
    bf16* WvT = WkT + H * DH * DH;

    prep_w<<<dim3(304), 256, 0, stream>>>(Wq, Wk, Wv, Wf, WqT, WkT, WvT, WfT);
    qkv_attn<<<dim3(512), 256, 0, stream>>>(X, mask, WqT, WkT, WvT, bq, bk, bv, Ob);
    fuse_mfma<<<dim3(D / 128, (B * T) / 128), 256, 0, stream>>>(Ob, WfT, bfv, out);
}